// Round 1
// baseline (525.278 us; speedup 1.0000x reference)
//
#include <hip/hip_runtime.h>
#include <hip/hip_bf16.h>

#define HC 256        // HEADS*OUT_CH
#define NEG_SLOPE 0.2f
#define BM 64
#define BK 64
#define LDK 72        // padded LDS k-stride (bf16 elems): 144B rows, 16B-aligned

typedef short short8_t __attribute__((ext_vector_type(8)));
typedef float float4_t __attribute__((ext_vector_type(4)));
typedef float float2_t __attribute__((ext_vector_type(2)));

__device__ __forceinline__ unsigned short f2bf(float f) {
  unsigned u = __float_as_uint(f);
  return (unsigned short)((u + 0x7fffu + ((u >> 16) & 1u)) >> 16);  // RNE
}
__device__ __forceinline__ float bf2f(unsigned short b) {
  return __uint_as_float(((unsigned)b) << 16);
}

// ---------------------------------------------------------------------------
// K0: Wt[n][k] = bf16(W[k][n]).  256x256, tiny.
// ---------------------------------------------------------------------------
__global__ void wt_kernel(const float* __restrict__ W, unsigned short* __restrict__ Wt)
{
  const int k = blockIdx.x;
  const int n = threadIdx.x;
  Wt[n * 256 + k] = f2bf(W[k * 256 + n]);
}

// ---------------------------------------------------------------------------
// K1: h = x @ W via bf16 MFMA (unchanged from 276.7us version).
// ---------------------------------------------------------------------------
__global__ __launch_bounds__(256) void gemm_mfma(
    const float* __restrict__ x, const unsigned short* __restrict__ Wt,
    const float* __restrict__ att_src, const float* __restrict__ att_dst,
    unsigned short* __restrict__ h, float* __restrict__ a_src,
    float* __restrict__ a_dst, int nnodes)
{
  __shared__ unsigned short As[BM * LDK];    // 9216 B
  __shared__ unsigned short Bs[256 * LDK];   // 36864 B
  const int t    = threadIdx.x;
  const int wv   = t >> 6;
  const int lane = t & 63;
  const int r0   = blockIdx.x * BM;

  float4_t acc[4][4] = {};   // [mt][nt]

  for (int k0 = 0; k0 < 256; k0 += BK) {
    __syncthreads();
    {
      const int row = t >> 2, kc = (t & 3) * 16;
      const int gr = r0 + row;
      float4 xv[4];
      if (gr < nnodes) {
        const float4* p = (const float4*)(x + (size_t)gr * 256 + k0 + kc);
        xv[0] = p[0]; xv[1] = p[1]; xv[2] = p[2]; xv[3] = p[3];
      } else {
        xv[0] = xv[1] = xv[2] = xv[3] = make_float4(0.f, 0.f, 0.f, 0.f);
      }
      const float* f = (const float*)xv;
      unsigned pk[8];
      #pragma unroll
      for (int i = 0; i < 8; ++i) {
        __hip_bfloat162 b2 = __float22bfloat162_rn(make_float2(f[2 * i], f[2 * i + 1]));
        pk[i] = *(unsigned*)&b2;
      }
      uint4* d = (uint4*)&As[row * LDK + kc];
      d[0] = make_uint4(pk[0], pk[1], pk[2], pk[3]);
      d[1] = make_uint4(pk[4], pk[5], pk[6], pk[7]);
    }
    #pragma unroll
    for (int it = 0; it < 4; ++it) {
      const int n = it * 64 + (t >> 2);
      const int kc = (t & 3) * 16;
      const uint4* g = (const uint4*)(Wt + (size_t)n * 256 + k0 + kc);
      uint4 v0 = g[0], v1 = g[1];
      uint4* d = (uint4*)&Bs[n * LDK + kc];
      d[0] = v0; d[1] = v1;
    }
    __syncthreads();

    #pragma unroll
    for (int ks = 0; ks < 2; ++ks) {
      const int ko = ks * 32 + (lane >> 4) * 8;
      short8_t af[4], bfr[4];
      #pragma unroll
      for (int mt = 0; mt < 4; ++mt)
        af[mt] = *(const short8_t*)&As[(16 * mt + (lane & 15)) * LDK + ko];
      #pragma unroll
      for (int nt = 0; nt < 4; ++nt)
        bfr[nt] = *(const short8_t*)&Bs[(64 * wv + 16 * nt + (lane & 15)) * LDK + ko];
      #pragma unroll
      for (int mt = 0; mt < 4; ++mt)
        #pragma unroll
        for (int nt = 0; nt < 4; ++nt)
          acc[mt][nt] = __builtin_amdgcn_mfma_f32_16x16x32_bf16(
              af[mt], bfr[nt], acc[mt][nt], 0, 0, 0);
    }
  }

  const int q = lane >> 4, l15 = lane & 15;
  float atts[4], attd[4];
  #pragma unroll
  for (int nt = 0; nt < 4; ++nt) {
    atts[nt] = att_src[wv * 64 + 16 * nt + l15];
    attd[nt] = att_dst[wv * 64 + 16 * nt + l15];
  }

  #pragma unroll
  for (int mt = 0; mt < 4; ++mt) {
    #pragma unroll
    for (int reg = 0; reg < 4; ++reg) {
      const int row = r0 + 16 * mt + 4 * q + reg;
      const bool ok = row < nnodes;
      float ps = 0.f, pd = 0.f;
      #pragma unroll
      for (int nt = 0; nt < 4; ++nt) {
        const float v = acc[mt][nt][reg];
        if (ok) h[(size_t)row * 256 + 64 * wv + 16 * nt + l15] = f2bf(v);
        ps += v * atts[nt];
        pd += v * attd[nt];
      }
      #pragma unroll
      for (int off = 8; off; off >>= 1) {
        ps += __shfl_down(ps, off, 16);
        pd += __shfl_down(pd, off, 16);
      }
      if (ok && l15 == 0) {
        a_src[row * 4 + wv] = ps;
        a_dst[row * 4 + wv] = pd;
      }
    }
  }
}

// ---------------------------------------------------------------------------
// CSR build (unchanged)
// ---------------------------------------------------------------------------
__global__ void deg_count(const int* __restrict__ ei, int* __restrict__ deg, int E)
{
  const int e = blockIdx.x * blockDim.x + threadIdx.x;
  if (e >= E) return;
  atomicAdd(&deg[ei[E + e]], 1);
}

__global__ __launch_bounds__(256) void scan_p1(const int* __restrict__ deg,
                                               int* __restrict__ bsum, int n)
{
  __shared__ int ws[4];
  const int t = threadIdx.x, lane = t & 63, wv = t >> 6;
  const int base = blockIdx.x * 1024 + t * 4;
  int4 v = make_int4(0, 0, 0, 0);
  if (base + 3 < n) v = *(const int4*)&deg[base];
  else {
    if (base + 0 < n) v.x = deg[base + 0];
    if (base + 1 < n) v.y = deg[base + 1];
    if (base + 2 < n) v.z = deg[base + 2];
  }
  int s = (v.x + v.y) + (v.z + v.w);
  #pragma unroll
  for (int off = 32; off; off >>= 1) s += __shfl_down(s, off, 64);
  if (lane == 0) ws[wv] = s;
  __syncthreads();
  if (t == 0) bsum[blockIdx.x] = (ws[0] + ws[1]) + (ws[2] + ws[3]);
}

__global__ __launch_bounds__(1024) void scan_p2(const int* __restrict__ bsum,
                                                int* __restrict__ boff,
                                                int* __restrict__ rowptr,
                                                int nb, int n)
{
  __shared__ int wsum[16], woff[16];
  const int t = threadIdx.x, lane = t & 63, wv = t >> 6;
  int v = (t < nb) ? bsum[t] : 0;
  int sc = v;
  #pragma unroll
  for (int off = 1; off < 64; off <<= 1) {
    int u = __shfl_up(sc, off, 64);
    if (lane >= off) sc += u;
  }
  if (lane == 63) wsum[wv] = sc;
  __syncthreads();
  if (t == 0) {
    int run = 0;
    #pragma unroll
    for (int i = 0; i < 16; ++i) { int x = wsum[i]; woff[i] = run; run += x; }
    rowptr[n] = run;
  }
  __syncthreads();
  if (t < nb) boff[t] = woff[wv] + sc - v;
}

__global__ __launch_bounds__(256) void scan_p3(const int* __restrict__ deg,
                                               const int* __restrict__ boff,
                                               int* __restrict__ rowptr,
                                               int* __restrict__ cursor, int n)
{
  __shared__ int wsum[4], woff[4];
  const int t = threadIdx.x, lane = t & 63, wv = t >> 6;
  const int base = blockIdx.x * 1024 + t * 4;
  int4 v = make_int4(0, 0, 0, 0);
  if (base + 3 < n) v = *(const int4*)&deg[base];
  else {
    if (base + 0 < n) v.x = deg[base + 0];
    if (base + 1 < n) v.y = deg[base + 1];
    if (base + 2 < n) v.z = deg[base + 2];
  }
  const int s = (v.x + v.y) + (v.z + v.w);
  int sc = s;
  #pragma unroll
  for (int off = 1; off < 64; off <<= 1) {
    int u = __shfl_up(sc, off, 64);
    if (lane >= off) sc += u;
  }
  if (lane == 63) wsum[wv] = sc;
  __syncthreads();
  if (t == 0) {
    int run = 0;
    #pragma unroll
    for (int i = 0; i < 4; ++i) { int x = wsum[i]; woff[i] = run; run += x; }
  }
  __syncthreads();
  int excl = boff[blockIdx.x] + woff[wv] + (sc - s);
  int4 r;
  r.x = excl;
  r.y = r.x + v.x;
  r.z = r.y + v.y;
  r.w = r.z + v.z;
  if (base + 3 < n) {
    *(int4*)&rowptr[base] = r;
    *(int4*)&cursor[base] = r;
  } else {
    if (base + 0 < n) { rowptr[base + 0] = r.x; cursor[base + 0] = r.x; }
    if (base + 1 < n) { rowptr[base + 1] = r.y; cursor[base + 1] = r.y; }
    if (base + 2 < n) { rowptr[base + 2] = r.z; cursor[base + 2] = r.z; }
  }
}

// ---------------------------------------------------------------------------
// fill_csr, XCD-grouped as before; wexp now stored TRANSPOSED as 4 planes
// wexp[head*E + pos] so the channel-sliced gather streams 4B/edge/group
// instead of refetching whole 16B-stride lines.
// ---------------------------------------------------------------------------
__global__ __launch_bounds__(256) void fill_csr(
    const int* __restrict__ ei, const float* __restrict__ a_src,
    const float* __restrict__ a_dst, int* __restrict__ cursor,
    int* __restrict__ csr_src, float* __restrict__ wexp, int E, int nnodes)
{
  const int g    = blockIdx.x & 7;
  const int bg   = blockIdx.x >> 3;
  const int nbg  = gridDim.x >> 3;
  const int gsz  = (nnodes + 7) >> 3;
  const int dlo  = g * gsz;
  const int dhi  = min(dlo + gsz, nnodes);

  for (int e = bg * 256 + threadIdx.x; e < E; e += nbg * 256) {
    const int d = ei[E + e];
    if (d < dlo || d >= dhi) continue;
    const int s = ei[e];
    const int pos = atomicAdd(&cursor[d], 1);
    csr_src[pos] = s;
    const float4 as = ((const float4*)a_src)[s];
    const float4 ad = ((const float4*)a_dst)[d];
    float4 al;
    al.x = as.x + ad.x; al.y = as.y + ad.y;
    al.z = as.z + ad.z; al.w = as.w + ad.w;
    al.x = al.x > 0.f ? al.x : NEG_SLOPE * al.x;
    al.y = al.y > 0.f ? al.y : NEG_SLOPE * al.y;
    al.z = al.z > 0.f ? al.z : NEG_SLOPE * al.z;
    al.w = al.w > 0.f ? al.w : NEG_SLOPE * al.w;
    wexp[pos]         = expf(al.x);
    wexp[E + pos]     = expf(al.y);
    wexp[2 * E + pos] = expf(al.z);
    wexp[3 * E + pos] = expf(al.w);
  }
}

// ---------------------------------------------------------------------------
// K3: gather, CHANNEL-SLICED across XCDs.
// Group g = blockIdx&7 (lands on XCD g, round-robin dispatch) handles
// channels [32g, 32g+32) for ALL dst nodes. Its h-slice footprint is
// 50000*64B = 3.2MB < 4MiB per-XCD L2 -> the E*64B random h reads become
// L2 hits after compulsory misses (was the dominant FETCH: 197MB).
// csr/wexp streams (read once per XCD) + out stores are nontemporal so
// they don't evict the resident h-slice.
// Wave layout: 4 edges in flight (16 lanes each), lane covers 2 channels;
// cross-sub butterfly (xor 16/32) reduces acc+denominator at the end.
// ---------------------------------------------------------------------------
__global__ __launch_bounds__(256) void gather_kernel(
    const int* __restrict__ rowptr, const int* __restrict__ csr_src,
    const float* __restrict__ wexp_t, const unsigned short* __restrict__ h,
    const float* __restrict__ a_src, const float* __restrict__ a_dst,
    const float* __restrict__ bias, float* __restrict__ out, int n, int E)
{
  const int g    = blockIdx.x & 7;          // channel slice == XCD
  const int bg   = blockIdx.x >> 3;
  const int nbg  = gridDim.x >> 3;
  const int wave = threadIdx.x >> 6;
  const int lane = threadIdx.x & 63;
  const int head = g >> 1;                  // slice of 32ch = half a head
  const int sub  = lane >> 4;               // 4 edges concurrently per wave
  const int cb   = g * 32 + (lane & 15) * 2;  // this lane's 2 channels

  const float* __restrict__ wrow = wexp_t + (size_t)head * E;
  const float2_t b2 = *(const float2_t*)&bias[cb];

  for (int d = bg * 4 + wave; d < n; d += nbg * 4) {
    // self-loop (same alpha for all lanes; only sub 0 contributes pre-reduce)
    float alpha = a_src[d * 4 + head] + a_dst[d * 4 + head];
    alpha = alpha > 0.f ? alpha : NEG_SLOPE * alpha;
    const float wself = expf(alpha);

    float dsum = 0.f, ax = 0.f, ay = 0.f;
    if (sub == 0) {
      const ushort2 u = *(const ushort2*)&h[(size_t)d * 256 + cb];
      dsum = wself;
      ax = wself * bf2f(u.x);
      ay = wself * bf2f(u.y);
    }

    const int end = rowptr[d + 1];
    for (int j = rowptr[d] + sub; j < end; j += 4) {
      const int   s = __builtin_nontemporal_load(&csr_src[j]);
      const float w = __builtin_nontemporal_load(&wrow[j]);
      const ushort2 u = *(const ushort2*)&h[(size_t)s * 256 + cb];  // cached!
      dsum += w;
      ax += w * bf2f(u.x);
      ay += w * bf2f(u.y);
    }

    // reduce across the 4 sub-groups
    dsum += __shfl_xor(dsum, 16); dsum += __shfl_xor(dsum, 32);
    ax   += __shfl_xor(ax, 16);   ax   += __shfl_xor(ax, 32);
    ay   += __shfl_xor(ay, 16);   ay   += __shfl_xor(ay, 32);

    if (lane < 16) {
      const float inv = 1.f / (dsum + 1e-16f);
      float2_t o;
      o.x = ax * inv + b2.x; o.x = o.x > 0.f ? o.x : 0.f;
      o.y = ay * inv + b2.y; o.y = o.y > 0.f ? o.y : 0.f;
      __builtin_nontemporal_store(o, (float2_t*)&out[(size_t)d * 256 + cb]);
    }
  }
}

extern "C" void kernel_launch(void* const* d_in, const int* in_sizes, int n_in,
                              void* d_out, int out_size, void* d_ws, size_t ws_size,
                              hipStream_t stream)
{
  const float* x       = (const float*)d_in[0];
  const int*   ei      = (const int*)d_in[1];
  const float* W       = (const float*)d_in[2];
  const float* att_src = (const float*)d_in[3];
  const float* att_dst = (const float*)d_in[4];
  const float* bias    = (const float*)d_in[5];

  const int nnodes = in_sizes[0] / HC;   // 50000
  const int E      = in_sizes[1] / 2;    // 800000
  const int nb     = (nnodes + 1023) / 1024;   // scan blocks (49)

  float* out = (float*)d_out;
  char* ws = (char*)d_ws;
  // Workspace (~44 MB), all segments 16B-aligned:
  unsigned short* h  = (unsigned short*)ws;                          // nnodes*256 bf16
  float* a_src = (float*)(ws + (size_t)nnodes * HC * 2);             // nnodes*4 f32
  float* a_dst = a_src + (size_t)nnodes * 4;
  unsigned short* Wt = (unsigned short*)(a_dst + (size_t)nnodes * 4); // 256*256 bf16
  int* deg    = (int*)((char*)Wt + 256 * 256 * 2);                   // nnodes
  int* rowptr = deg + nnodes;                                        // nnodes+1 (pad x4)
  int* cursor = rowptr + ((nnodes + 1 + 3) & ~3);                    // nnodes
  int* bsum   = cursor + nnodes;                                     // nb
  int* boff   = bsum + ((nb + 3) & ~3);                              // nb
  float* wexp = (float*)(boff + ((nb + 3) & ~3));                    // 4*E f32 planes (12.8 MB)
  int* csr    = (int*)(wexp + (size_t)4 * E);                        // E

  hipMemsetAsync(deg, 0, (size_t)nnodes * sizeof(int), stream);

  wt_kernel<<<256, 256, 0, stream>>>(W, Wt);

  gemm_mfma<<<(nnodes + BM - 1) / BM, 256, 0, stream>>>(
      x, Wt, att_src, att_dst, h, a_src, a_dst, nnodes);

  deg_count<<<(E + 255) / 256, 256, 0, stream>>>(ei, deg, E);
  scan_p1<<<nb, 256, 0, stream>>>(deg, bsum, nnodes);
  scan_p2<<<1, 1024, 0, stream>>>(bsum, boff, rowptr, nb, nnodes);
  scan_p3<<<nb, 256, 0, stream>>>(deg, boff, rowptr, cursor, nnodes);

  fill_csr<<<1024, 256, 0, stream>>>(ei, a_src, a_dst, cursor, csr,
                                     wexp, E, nnodes);

  // 8 groups x 2048 blocks, grid-stride over dsts within each group
  gather_kernel<<<8 * 2048, 256, 0, stream>>>(
      rowptr, csr, wexp, h, a_src, a_dst, bias, out, nnodes, E);
}

// Round 2
// 441.284 us; speedup vs baseline: 1.1903x; 1.1903x over previous
//
#include <hip/hip_runtime.h>
#include <hip/hip_bf16.h>

#define HC 256        // HEADS*OUT_CH
#define NEG_SLOPE 0.2f
#define BM 64
#define BK 64
#define LDK 72        // padded LDS k-stride (bf16 elems): 144B rows, 16B-aligned

typedef short short8_t __attribute__((ext_vector_type(8)));
typedef float float4_t __attribute__((ext_vector_type(4)));
typedef float float2_t __attribute__((ext_vector_type(2)));
typedef int   int4_t   __attribute__((ext_vector_type(4)));

__device__ __forceinline__ unsigned short f2bf(float f) {
  unsigned u = __float_as_uint(f);
  return (unsigned short)((u + 0x7fffu + ((u >> 16) & 1u)) >> 16);  // RNE
}
__device__ __forceinline__ float bf2f(unsigned short b) {
  return __uint_as_float(((unsigned)b) << 16);
}

// ---------------------------------------------------------------------------
// K0: Wt[n][k] = bf16(W[k][n]).  256x256, tiny.
// ---------------------------------------------------------------------------
__global__ void wt_kernel(const float* __restrict__ W, unsigned short* __restrict__ Wt)
{
  const int k = blockIdx.x;
  const int n = threadIdx.x;
  Wt[n * 256 + k] = f2bf(W[k * 256 + n]);
}

// ---------------------------------------------------------------------------
// K1: h = x @ W via bf16 MFMA. Epilogue now writes h in SLICE-MAJOR layout:
// h_t[slice][node][32ch], slice = channel>>5. Each slice is a contiguous
// 3.2MB plane so the gather's per-XCD working set uses ALL L2 sets
// (round-1's row-major slice had stride 512B -> 1/8 of sets -> thrash).
// Store coalescing is unchanged (same 32B-per-16-lane chunks).
// ---------------------------------------------------------------------------
__global__ __launch_bounds__(256) void gemm_mfma(
    const float* __restrict__ x, const unsigned short* __restrict__ Wt,
    const float* __restrict__ att_src, const float* __restrict__ att_dst,
    unsigned short* __restrict__ h, float* __restrict__ a_src,
    float* __restrict__ a_dst, int nnodes)
{
  __shared__ unsigned short As[BM * LDK];    // 9216 B
  __shared__ unsigned short Bs[256 * LDK];   // 36864 B
  const int t    = threadIdx.x;
  const int wv   = t >> 6;
  const int lane = t & 63;
  const int r0   = blockIdx.x * BM;

  float4_t acc[4][4] = {};   // [mt][nt]

  for (int k0 = 0; k0 < 256; k0 += BK) {
    __syncthreads();
    {
      const int row = t >> 2, kc = (t & 3) * 16;
      const int gr = r0 + row;
      float4 xv[4];
      if (gr < nnodes) {
        const float4* p = (const float4*)(x + (size_t)gr * 256 + k0 + kc);
        xv[0] = p[0]; xv[1] = p[1]; xv[2] = p[2]; xv[3] = p[3];
      } else {
        xv[0] = xv[1] = xv[2] = xv[3] = make_float4(0.f, 0.f, 0.f, 0.f);
      }
      const float* f = (const float*)xv;
      unsigned pk[8];
      #pragma unroll
      for (int i = 0; i < 8; ++i) {
        __hip_bfloat162 b2 = __float22bfloat162_rn(make_float2(f[2 * i], f[2 * i + 1]));
        pk[i] = *(unsigned*)&b2;
      }
      uint4* d = (uint4*)&As[row * LDK + kc];
      d[0] = make_uint4(pk[0], pk[1], pk[2], pk[3]);
      d[1] = make_uint4(pk[4], pk[5], pk[6], pk[7]);
    }
    #pragma unroll
    for (int it = 0; it < 4; ++it) {
      const int n = it * 64 + (t >> 2);
      const int kc = (t & 3) * 16;
      const uint4* g = (const uint4*)(Wt + (size_t)n * 256 + k0 + kc);
      uint4 v0 = g[0], v1 = g[1];
      uint4* d = (uint4*)&Bs[n * LDK + kc];
      d[0] = v0; d[1] = v1;
    }
    __syncthreads();

    #pragma unroll
    for (int ks = 0; ks < 2; ++ks) {
      const int ko = ks * 32 + (lane >> 4) * 8;
      short8_t af[4], bfr[4];
      #pragma unroll
      for (int mt = 0; mt < 4; ++mt)
        af[mt] = *(const short8_t*)&As[(16 * mt + (lane & 15)) * LDK + ko];
      #pragma unroll
      for (int nt = 0; nt < 4; ++nt)
        bfr[nt] = *(const short8_t*)&Bs[(64 * wv + 16 * nt + (lane & 15)) * LDK + ko];
      #pragma unroll
      for (int mt = 0; mt < 4; ++mt)
        #pragma unroll
        for (int nt = 0; nt < 4; ++nt)
          acc[mt][nt] = __builtin_amdgcn_mfma_f32_16x16x32_bf16(
              af[mt], bfr[nt], acc[mt][nt], 0, 0, 0);
    }
  }

  const int q = lane >> 4, l15 = lane & 15;
  const size_t nn32 = (size_t)nnodes * 32;
  float atts[4], attd[4];
  #pragma unroll
  for (int nt = 0; nt < 4; ++nt) {
    atts[nt] = att_src[wv * 64 + 16 * nt + l15];
    attd[nt] = att_dst[wv * 64 + 16 * nt + l15];
  }

  #pragma unroll
  for (int mt = 0; mt < 4; ++mt) {
    #pragma unroll
    for (int reg = 0; reg < 4; ++reg) {
      const int row = r0 + 16 * mt + 4 * q + reg;
      const bool ok = row < nnodes;
      float ps = 0.f, pd = 0.f;
      #pragma unroll
      for (int nt = 0; nt < 4; ++nt) {
        const float v = acc[mt][nt][reg];
        if (ok) {
          const int g2 = 2 * wv + (nt >> 1);          // slice = channel>>5
          const int cc = 16 * (nt & 1) + l15;         // channel&31
          h[(size_t)g2 * nn32 + (size_t)row * 32 + cc] = f2bf(v);
        }
        ps += v * atts[nt];
        pd += v * attd[nt];
      }
      #pragma unroll
      for (int off = 8; off; off >>= 1) {
        ps += __shfl_down(ps, off, 16);
        pd += __shfl_down(pd, off, 16);
      }
      if (ok && l15 == 0) {
        a_src[row * 4 + wv] = ps;
        a_dst[row * 4 + wv] = pd;
      }
    }
  }
}

// ---------------------------------------------------------------------------
// CSR build (unchanged)
// ---------------------------------------------------------------------------
__global__ void deg_count(const int* __restrict__ ei, int* __restrict__ deg, int E)
{
  const int e = blockIdx.x * blockDim.x + threadIdx.x;
  if (e >= E) return;
  atomicAdd(&deg[ei[E + e]], 1);
}

__global__ __launch_bounds__(256) void scan_p1(const int* __restrict__ deg,
                                               int* __restrict__ bsum, int n)
{
  __shared__ int ws[4];
  const int t = threadIdx.x, lane = t & 63, wv = t >> 6;
  const int base = blockIdx.x * 1024 + t * 4;
  int4 v = make_int4(0, 0, 0, 0);
  if (base + 3 < n) v = *(const int4*)&deg[base];
  else {
    if (base + 0 < n) v.x = deg[base + 0];
    if (base + 1 < n) v.y = deg[base + 1];
    if (base + 2 < n) v.z = deg[base + 2];
  }
  int s = (v.x + v.y) + (v.z + v.w);
  #pragma unroll
  for (int off = 32; off; off >>= 1) s += __shfl_down(s, off, 64);
  if (lane == 0) ws[wv] = s;
  __syncthreads();
  if (t == 0) bsum[blockIdx.x] = (ws[0] + ws[1]) + (ws[2] + ws[3]);
}

__global__ __launch_bounds__(1024) void scan_p2(const int* __restrict__ bsum,
                                                int* __restrict__ boff,
                                                int* __restrict__ rowptr,
                                                int nb, int n)
{
  __shared__ int wsum[16], woff[16];
  const int t = threadIdx.x, lane = t & 63, wv = t >> 6;
  int v = (t < nb) ? bsum[t] : 0;
  int sc = v;
  #pragma unroll
  for (int off = 1; off < 64; off <<= 1) {
    int u = __shfl_up(sc, off, 64);
    if (lane >= off) sc += u;
  }
  if (lane == 63) wsum[wv] = sc;
  __syncthreads();
  if (t == 0) {
    int run = 0;
    #pragma unroll
    for (int i = 0; i < 16; ++i) { int x = wsum[i]; woff[i] = run; run += x; }
    rowptr[n] = run;
  }
  __syncthreads();
  if (t < nb) boff[t] = woff[wv] + sc - v;
}

__global__ __launch_bounds__(256) void scan_p3(const int* __restrict__ deg,
                                               const int* __restrict__ boff,
                                               int* __restrict__ rowptr,
                                               int* __restrict__ cursor, int n)
{
  __shared__ int wsum[4], woff[4];
  const int t = threadIdx.x, lane = t & 63, wv = t >> 6;
  const int base = blockIdx.x * 1024 + t * 4;
  int4 v = make_int4(0, 0, 0, 0);
  if (base + 3 < n) v = *(const int4*)&deg[base];
  else {
    if (base + 0 < n) v.x = deg[base + 0];
    if (base + 1 < n) v.y = deg[base + 1];
    if (base + 2 < n) v.z = deg[base + 2];
  }
  const int s = (v.x + v.y) + (v.z + v.w);
  int sc = s;
  #pragma unroll
  for (int off = 1; off < 64; off <<= 1) {
    int u = __shfl_up(sc, off, 64);
    if (lane >= off) sc += u;
  }
  if (lane == 63) wsum[wv] = sc;
  __syncthreads();
  if (t == 0) {
    int run = 0;
    #pragma unroll
    for (int i = 0; i < 4; ++i) { int x = wsum[i]; woff[i] = run; run += x; }
  }
  __syncthreads();
  int excl = boff[blockIdx.x] + woff[wv] + (sc - s);
  int4 r;
  r.x = excl;
  r.y = r.x + v.x;
  r.z = r.y + v.y;
  r.w = r.z + v.z;
  if (base + 3 < n) {
    *(int4*)&rowptr[base] = r;
    *(int4*)&cursor[base] = r;
  } else {
    if (base + 0 < n) { rowptr[base + 0] = r.x; cursor[base + 0] = r.x; }
    if (base + 1 < n) { rowptr[base + 1] = r.y; cursor[base + 1] = r.y; }
    if (base + 2 < n) { rowptr[base + 2] = r.z; cursor[base + 2] = r.z; }
  }
}

// ---------------------------------------------------------------------------
// fill_csr, XCD-grouped; wexp stored TRANSPOSED as 4 planes wexp[head*E+pos]
// so each gather slice streams 4B/edge instead of 16B-stride pieces.
// ---------------------------------------------------------------------------
__global__ __launch_bounds__(256) void fill_csr(
    const int* __restrict__ ei, const float* __restrict__ a_src,
    const float* __restrict__ a_dst, int* __restrict__ cursor,
    int* __restrict__ csr_src, float* __restrict__ wexp, int E, int nnodes)
{
  const int g    = blockIdx.x & 7;
  const int bg   = blockIdx.x >> 3;
  const int nbg  = gridDim.x >> 3;
  const int gsz  = (nnodes + 7) >> 3;
  const int dlo  = g * gsz;
  const int dhi  = min(dlo + gsz, nnodes);

  for (int e = bg * 256 + threadIdx.x; e < E; e += nbg * 256) {
    const int d = ei[E + e];
    if (d < dlo || d >= dhi) continue;
    const int s = ei[e];
    const int pos = atomicAdd(&cursor[d], 1);
    csr_src[pos] = s;
    const float4 as = ((const float4*)a_src)[s];
    const float4 ad = ((const float4*)a_dst)[d];
    float4 al;
    al.x = as.x + ad.x; al.y = as.y + ad.y;
    al.z = as.z + ad.z; al.w = as.w + ad.w;
    al.x = al.x > 0.f ? al.x : NEG_SLOPE * al.x;
    al.y = al.y > 0.f ? al.y : NEG_SLOPE * al.y;
    al.z = al.z > 0.f ? al.z : NEG_SLOPE * al.z;
    al.w = al.w > 0.f ? al.w : NEG_SLOPE * al.w;
    wexp[pos]         = expf(al.x);
    wexp[E + pos]     = expf(al.y);
    wexp[2 * E + pos] = expf(al.z);
    wexp[3 * E + pos] = expf(al.w);
  }
}

// ---------------------------------------------------------------------------
// K3: gather, CHANNEL-SLICED across XCDs, slice-major h.
// Group g = blockIdx&7 (XCD g via round-robin dispatch) handles channels
// [32g,32g+32) for ALL dsts. Its h-plane is the CONTIGUOUS 3.2MB region
// h_t[g][*][*] -> fits a 4MiB XCD L2 with full set utilization (round-1's
// 512B-stride slice aliased into 1/8 of the sets and thrashed).
// MLP restored to round-0 levels: each of 4 subs owns a contiguous quarter
// of the edge range and processes 4 edges/iter (int4 csr + float4 wexp +
// 4 independent 64B h-gathers) -> 16 outstanding gathers/wave.
// csr/wexp streams + out stores are nontemporal so they don't evict h.
// ---------------------------------------------------------------------------
__global__ __launch_bounds__(256) void gather_kernel(
    const int* __restrict__ rowptr, const int* __restrict__ csr_src,
    const float* __restrict__ wexp_t, const unsigned short* __restrict__ h,
    const float* __restrict__ a_src, const float* __restrict__ a_dst,
    const float* __restrict__ bias, float* __restrict__ out, int n, int E)
{
  const int g    = blockIdx.x & 7;          // channel slice == XCD
  const int bg   = blockIdx.x >> 3;
  const int nbg  = gridDim.x >> 3;
  const int wave = threadIdx.x >> 6;
  const int lane = threadIdx.x & 63;
  const int head = g >> 1;                  // slice of 32ch = half a head
  const int sub  = lane >> 4;               // 4 contiguous edge-chunks per wave
  const int co   = (lane & 15) * 2;         // this lane's 2 channels in slice
  const int cb   = g * 32 + co;             // global channel index

  const size_t nn32 = (size_t)n * 32;
  const unsigned short* __restrict__ hs = h + (size_t)g * nn32;  // slice plane
  const float* __restrict__ wrow = wexp_t + (size_t)head * E;
  const float2_t b2 = *(const float2_t*)&bias[cb];

  for (int d = bg * 4 + wave; d < n; d += nbg * 4) {
    float alpha = a_src[d * 4 + head] + a_dst[d * 4 + head];
    alpha = alpha > 0.f ? alpha : NEG_SLOPE * alpha;
    const float wself = expf(alpha);

    float dsum = 0.f, ax = 0.f, ay = 0.f;
    if (sub == 0) {
      const ushort2 u = *(const ushort2*)&hs[(size_t)d * 32 + co];
      dsum = wself;
      ax = wself * bf2f(u.x);
      ay = wself * bf2f(u.y);
    }

    // contiguous per-sub partition of [beg,end)
    const int beg = rowptr[d];
    const int cnt = rowptr[d + 1] - beg;
    const int base = cnt >> 2, rem = cnt & 3;
    int j        = beg + sub * base + min(sub, rem);
    const int hi = j + base + (sub < rem ? 1 : 0);

    for (; j + 3 < hi; j += 4) {
      const int4_t  s4 = __builtin_nontemporal_load((const int4_t*)&csr_src[j]);
      const float4_t w4 = __builtin_nontemporal_load((const float4_t*)&wrow[j]);
      const ushort2 u0 = *(const ushort2*)&hs[(size_t)s4.x * 32 + co];
      const ushort2 u1 = *(const ushort2*)&hs[(size_t)s4.y * 32 + co];
      const ushort2 u2 = *(const ushort2*)&hs[(size_t)s4.z * 32 + co];
      const ushort2 u3 = *(const ushort2*)&hs[(size_t)s4.w * 32 + co];
      dsum += (w4.x + w4.y) + (w4.z + w4.w);
      ax += w4.x * bf2f(u0.x) + w4.y * bf2f(u1.x) + w4.z * bf2f(u2.x) + w4.w * bf2f(u3.x);
      ay += w4.x * bf2f(u0.y) + w4.y * bf2f(u1.y) + w4.z * bf2f(u2.y) + w4.w * bf2f(u3.y);
    }
    for (; j < hi; ++j) {
      const int   s = __builtin_nontemporal_load(&csr_src[j]);
      const float w = __builtin_nontemporal_load(&wrow[j]);
      const ushort2 u = *(const ushort2*)&hs[(size_t)s * 32 + co];
      dsum += w;
      ax += w * bf2f(u.x);
      ay += w * bf2f(u.y);
    }

    // reduce across the 4 sub-groups
    dsum += __shfl_xor(dsum, 16); dsum += __shfl_xor(dsum, 32);
    ax   += __shfl_xor(ax, 16);   ax   += __shfl_xor(ax, 32);
    ay   += __shfl_xor(ay, 16);   ay   += __shfl_xor(ay, 32);

    if (lane < 16) {
      const float inv = 1.f / (dsum + 1e-16f);
      float2_t o;
      o.x = ax * inv + b2.x; o.x = o.x > 0.f ? o.x : 0.f;
      o.y = ay * inv + b2.y; o.y = o.y > 0.f ? o.y : 0.f;
      __builtin_nontemporal_store(o, (float2_t*)&out[(size_t)d * 256 + cb]);
    }
  }
}

extern "C" void kernel_launch(void* const* d_in, const int* in_sizes, int n_in,
                              void* d_out, int out_size, void* d_ws, size_t ws_size,
                              hipStream_t stream)
{
  const float* x       = (const float*)d_in[0];
  const int*   ei      = (const int*)d_in[1];
  const float* W       = (const float*)d_in[2];
  const float* att_src = (const float*)d_in[3];
  const float* att_dst = (const float*)d_in[4];
  const float* bias    = (const float*)d_in[5];

  const int nnodes = in_sizes[0] / HC;   // 50000
  const int E      = in_sizes[1] / 2;    // 800000
  const int nb     = (nnodes + 1023) / 1024;   // scan blocks (49)

  float* out = (float*)d_out;
  char* ws = (char*)d_ws;
  // Workspace (~44 MB), all segments 16B-aligned:
  unsigned short* h  = (unsigned short*)ws;                          // nnodes*256 bf16 (slice-major)
  float* a_src = (float*)(ws + (size_t)nnodes * HC * 2);             // nnodes*4 f32
  float* a_dst = a_src + (size_t)nnodes * 4;
  unsigned short* Wt = (unsigned short*)(a_dst + (size_t)nnodes * 4); // 256*256 bf16
  int* deg    = (int*)((char*)Wt + 256 * 256 * 2);                   // nnodes
  int* rowptr = deg + nnodes;                                        // nnodes+1 (pad x4)
  int* cursor = rowptr + ((nnodes + 1 + 3) & ~3);                    // nnodes
  int* bsum   = cursor + nnodes;                                     // nb
  int* boff   = bsum + ((nb + 3) & ~3);                              // nb
  float* wexp = (float*)(boff + ((nb + 3) & ~3));                    // 4*E f32 planes (12.8 MB)
  int* csr    = (int*)(wexp + (size_t)4 * E);                        // E

  hipMemsetAsync(deg, 0, (size_t)nnodes * sizeof(int), stream);

  wt_kernel<<<256, 256, 0, stream>>>(W, Wt);

  gemm_mfma<<<(nnodes + BM - 1) / BM, 256, 0, stream>>>(
      x, Wt, att_src, att_dst, h, a_src, a_dst, nnodes);

  deg_count<<<(E + 255) / 256, 256, 0, stream>>>(ei, deg, E);
  scan_p1<<<nb, 256, 0, stream>>>(deg, bsum, nnodes);
  scan_p2<<<1, 1024, 0, stream>>>(bsum, boff, rowptr, nb, nnodes);
  scan_p3<<<nb, 256, 0, stream>>>(deg, boff, rowptr, cursor, nnodes);

  fill_csr<<<1024, 256, 0, stream>>>(ei, a_src, a_dst, cursor, csr,
                                     wexp, E, nnodes);

  // 8 slice-groups x 2048 blocks, grid-stride over dsts within each group
  gather_kernel<<<8 * 2048, 256, 0, stream>>>(
      rowptr, csr, wexp, h, a_src, a_dst, bias, out, nnodes, E);
}